// Round 1
// 1000.115 us; speedup vs baseline: 1.2120x; 1.2120x over previous
//
#include <hip/hip_runtime.h>

// ---------------- problem constants ----------------
#define NN   128
#define CC   256
#define MH   28
#define MW   28
#define HW   784        // 28*28
#define KCLS 80
#define PP   196
#define SHH  200
#define SWW  200
#define SPIX 40000      // 200*200
#define FCIN 416        // C + 2K

typedef __attribute__((ext_vector_type(8))) short short8;
typedef __attribute__((ext_vector_type(4))) float f32x4;

__device__ __forceinline__ unsigned short f2bf(float x) {
  unsigned u = __float_as_uint(x);
  unsigned r = (u + 0x7fffu + ((u >> 16) & 1u)) >> 16;
  return (unsigned short)r;
}
__device__ __forceinline__ float bf2f(unsigned short h) {
  return __uint_as_float((unsigned)h << 16);
}

// ---- weight fp32->bf16 convert (concatenated blob) --------------------------
// layout: [w_sem 65536][w_fuse 65536][fc_w0 106496][fc_w1][fc_w2][w_log]
//         [w_cat = w_inst;w_det 40960]
#define OW_SEM  0
#define OW_FUSE 65536
#define OW_FC0  131072
#define OW_FC1  237568
#define OW_FC2  344064
#define OW_LOG  450560
#define OW_CAT  557056
#define OW_TOT  598016
__global__ void wconv_k(const float* __restrict__ wsem, const float* __restrict__ wfuse,
                        const float* __restrict__ w0, const float* __restrict__ w1,
                        const float* __restrict__ w2, const float* __restrict__ wlog,
                        const float* __restrict__ wi, const float* __restrict__ wd,
                        const float* __restrict__ bi, const float* __restrict__ bd,
                        unsigned short* __restrict__ out, float* __restrict__ bcat) {
  const int tid0 = blockIdx.x * blockDim.x + threadIdx.x;
  if (tid0 < KCLS) bcat[tid0] = bi[tid0];
  else if (tid0 < 2 * KCLS) bcat[tid0] = bd[tid0 - KCLS];
  for (int i = tid0; i < OW_TOT; i += gridDim.x * blockDim.x) {
    float v;
    if (i < OW_FUSE) v = wsem[i];
    else if (i < OW_FC0) v = wfuse[i - OW_FUSE];
    else if (i < OW_FC1) v = w0[i - OW_FC0];
    else if (i < OW_FC2) v = w1[i - OW_FC1];
    else if (i < OW_LOG) v = w2[i - OW_FC2];
    else if (i < OW_CAT) v = wlog[i - OW_LOG];
    else if (i < OW_CAT + KCLS * 256) v = wi[i - OW_CAT];
    else v = wd[i - OW_CAT - KCLS * 256];
    out[i] = f2bf(v);
  }
}

// ---- transpose+convert: src fp32 [256][P] (c-major) -> dst bf16 [P][256] ----
__global__ __launch_bounds__(256) void transpose_bf16_k(
    const float* __restrict__ src, unsigned short* __restrict__ dst, int P) {
  __shared__ float T[64][69];
  const int t = threadIdx.x;
  src += (size_t)blockIdx.z * 256 * P;
  dst += (size_t)blockIdx.z * P * 256;
  const int p0 = blockIdx.x * 64, c0 = blockIdx.y * 64;
#pragma unroll
  for (int it = 0; it < 16; ++it) {
    int idx = it * 256 + t, c = idx >> 6, p = idx & 63;
    T[c][p] = (p0 + p < P) ? src[(size_t)(c0 + c) * P + p0 + p] : 0.f;
  }
  __syncthreads();
#pragma unroll
  for (int it = 0; it < 16; ++it) {
    int idx = it * 256 + t, p = idx >> 6, c = idx & 63;
    if (p0 + p < P) dst[(size_t)(p0 + p) * 256 + c0 + c] = f2bf(T[c][p]);
  }
}

// ---- generic MFMA bf16 GEMM: D[m][n] = A[m][:] . B[n][:] (both k-innermost) -
// block tile 128x128, 4 waves, wave tile 64x64 (4x4 frags of 16x16x32).
// ASRC: 1 = A bf16 rows; 2 = A bf16 rows gathered via pidx from refined_t
//       ([n][hw][256]; row gm -> (gm/PP, pidx[gm])).
// EPI:  0 = mlp    (relu, bf16 out [m][FCIN] cols 0..255, bias[n])
//       1 = logits (scatter bf16 rows into refined_t via pidx, bias[n], no relu)
//       3 = fuse   (relu, fp32 out [m*HW + n] per batch z, bias[m])
//       4 = sem    (relu, bf16 out [m][256], bias[n])
//       5 = ctail  (no relu, bf16 out to BOTH X(outh) and Y(outf cast) tails,
//                   cols 256+go, bias[go], guard go<N)
template <int ASRC, int EPI>
__global__ __launch_bounds__(256) void gemm_mfma_k(
    const void* __restrict__ Ap, const unsigned short* __restrict__ Bmat,
    const float* __restrict__ bias, float* __restrict__ outf,
    unsigned short* __restrict__ outh, const int* __restrict__ pidx,
    int M, int N, int K, int lda, int ldb) {
  __shared__ __align__(16) unsigned short Abuf[128 * 40];
  __shared__ __align__(16) unsigned short Bbuf[128 * 40];
  const int t = threadIdx.x;
  const int m0 = blockIdx.x * 128, n0 = blockIdx.y * 128;
  if (EPI == 3) {
    Bmat += (size_t)blockIdx.z * HW * 256;
    outf += (size_t)blockIdx.z * CC * HW;
  }
  const unsigned short* Ah = (const unsigned short*)Ap;
  const int wave = t >> 6, lane = t & 63, lq = lane >> 4, lr = lane & 15;
  const int msub = (wave & 1) * 64, nsub = (wave >> 1) * 64;
  f32x4 acc[4][4] = {};
  for (int kc = 0; kc < K; kc += 32) {
    // stage A tile (128 rows x 32 k) -> Abuf[r][k], row stride 40
#pragma unroll
    for (int it = 0; it < 4; ++it) {
      const int idx = it * 256 + t, r = idx >> 3, jg = idx & 7;
      const int gm = m0 + r;
      ushort4 h = make_ushort4(0, 0, 0, 0);
      if (ASRC == 1) {
        if (gm < M) h = *(const ushort4*)&Ah[(size_t)gm * lda + kc + jg * 4];
      } else {  // ASRC == 2: indirect row gather
        if (gm < M) {
          const int nimg = gm / PP;
          const int srow = pidx[gm];
          h = *(const ushort4*)&Ah[((size_t)nimg * HW + srow) * 256 + kc + jg * 4];
        }
      }
      *(ushort4*)&Abuf[r * 40 + jg * 4] = h;
    }
    // stage B tile
#pragma unroll
    for (int it = 0; it < 4; ++it) {
      const int idx = it * 256 + t, r = idx >> 3, jg = idx & 7;
      const int gn = n0 + r;
      ushort4 h = make_ushort4(0, 0, 0, 0);
      if (gn < N) h = *(const ushort4*)&Bmat[(size_t)gn * ldb + kc + jg * 4];
      *(ushort4*)&Bbuf[r * 40 + jg * 4] = h;
    }
    __syncthreads();
    short8 af[4], bfr[4];
#pragma unroll
    for (int i = 0; i < 4; ++i)
      af[i] = *(const short8*)&Abuf[(msub + i * 16 + lr) * 40 + lq * 8];
#pragma unroll
    for (int f = 0; f < 4; ++f)
      bfr[f] = *(const short8*)&Bbuf[(nsub + f * 16 + lr) * 40 + lq * 8];
#pragma unroll
    for (int i = 0; i < 4; ++i)
#pragma unroll
      for (int f = 0; f < 4; ++f)
        acc[i][f] = __builtin_amdgcn_mfma_f32_16x16x32_bf16(af[i], bfr[f],
                                                            acc[i][f], 0, 0, 0);
    __syncthreads();
  }
  // epilogue: C/D layout col=lane&15, row=lq*4+reg  [verified m89/m91]
#pragma unroll
  for (int i = 0; i < 4; ++i) {
#pragma unroll
    for (int r = 0; r < 4; ++r) {
      const int gm = m0 + msub + i * 16 + lq * 4 + r;
      if (EPI == 0) {
        if (gm < M) {
#pragma unroll
          for (int f = 0; f < 4; ++f) {
            const int go = n0 + nsub + f * 16 + lr;
            outh[(size_t)gm * FCIN + go] = f2bf(fmaxf(acc[i][f][r] + bias[go], 0.f));
          }
        }
      } else if (EPI == 1) {
        if (gm < M) {
          const int nimg = gm / PP;
          const int sidx = pidx[gm];
          unsigned short* dst = outh + ((size_t)nimg * HW + sidx) * 256;
#pragma unroll
          for (int f = 0; f < 4; ++f) {
            const int go = n0 + nsub + f * 16 + lr;
            dst[go] = f2bf(acc[i][f][r] + bias[go]);
          }
        }
      } else if (EPI == 3) {  // m = out channel, n = spatial
        const float bb = bias[gm];
#pragma unroll
        for (int f = 0; f < 4; ++f) {
          const int gs = n0 + nsub + f * 16 + lr;
          if (gs < N) outf[(size_t)gm * HW + gs] = fmaxf(acc[i][f][r] + bb, 0.f);
        }
      } else if (EPI == 4) {
        if (gm < M) {
#pragma unroll
          for (int f = 0; f < 4; ++f) {
            const int go = n0 + nsub + f * 16 + lr;
            outh[(size_t)gm * 256 + go] = f2bf(fmaxf(acc[i][f][r] + bias[go], 0.f));
          }
        }
      } else {  // EPI == 5
        if (gm < M) {
          unsigned short* dx = outh + (size_t)gm * FCIN + 256;
          unsigned short* dy = (unsigned short*)outf + (size_t)gm * FCIN + 256;
#pragma unroll
          for (int f = 0; f < 4; ++f) {
            const int go = n0 + nsub + f * 16 + lr;
            if (go < N) {
              const unsigned short v = f2bf(acc[i][f][r] + bias[go]);
              dx[go] = v;
              dy[go] = v;
            }
          }
        }
      }
    }
  }
}

// ---------------- K2: class-selected inst/det maps (outputs 0 & 1) ----------
// fp64 accumulate so our top-k ranking matches the high-precision reference.
__global__ __launch_bounds__(256) void select_maps_k(
    const float* __restrict__ inst, const int* __restrict__ labels,
    const float* __restrict__ w_inst, const float* __restrict__ b_inst,
    const float* __restrict__ w_det, const float* __restrict__ b_det,
    float* __restrict__ out0, float* __restrict__ out1) {
  const int n = blockIdx.x;
  const int s = blockIdx.y * 196 + threadIdx.x;
  if (threadIdx.x >= 196) return;
  const int lab = labels[n];
  const float* fi = inst + (size_t)n * CC * HW + s;
  const float* wi = w_inst + lab * 256;
  const float* wd = w_det + lab * 256;
  double ai = 0.0, ad = 0.0;
  for (int c = 0; c < 256; ++c) {
    const float v = fi[c * HW];
    ai += (double)v * (double)wi[c];
    ad += (double)v * (double)wd[c];
  }
  out0[n * HW + s] = (float)(ai + (double)b_inst[lab]);
  out1[n * HW + s] = (float)(ad + (double)b_det[lab]);
}

// ---------------- K3: per-n top-196 of 784 via bitonic sort ------------------
__global__ __launch_bounds__(256) void topk_k(const float* __restrict__ det,
                                              int* __restrict__ pidx) {
  __shared__ unsigned long long keys[1024];
  const int n = blockIdx.x;
  for (int i = threadIdx.x; i < 1024; i += 256) {
    unsigned long long kk = 0ull;
    if (i < HW) {
      unsigned u = __float_as_uint(det[n * HW + i]);
      u = (u & 0x80000000u) ? ~u : (u | 0x80000000u);
      kk = ((unsigned long long)u << 32) | (unsigned)(1023 - i);
    }
    keys[i] = kk;
  }
  __syncthreads();
  for (int k = 2; k <= 1024; k <<= 1) {
    for (int j = k >> 1; j > 0; j >>= 1) {
      for (int i = threadIdx.x; i < 1024; i += 256) {
        const int l = i ^ j;
        if (l > i) {
          const bool up = ((i & k) == 0);
          unsigned long long a = keys[i], bb = keys[l];
          if ((a > bb) == up) { keys[i] = bb; keys[l] = a; }
        }
      }
      __syncthreads();
    }
  }
  for (int r = threadIdx.x; r < PP; r += 256)
    pidx[n * PP + r] = 1023 - (int)(keys[828 + r] & 1023ull);
}

// ---------------- K4b: bilinear-sample bf16 sem at roi points -> X head ------
__global__ __launch_bounds__(256) void fine_sample_k(
    const unsigned short* __restrict__ sem, const int* __restrict__ pidx,
    const float* __restrict__ rois, unsigned short* __restrict__ X) {
  const int n = blockIdx.x;
  const int t = threadIdx.x;
  const int p = blockIdx.y * 8 + (t >> 5);
  const int c0 = (t & 31) * 8;
  if (p >= PP) return;
  const int idx = pidx[n * PP + p];
  const float rx = ((float)(idx % MW) + 0.5f) / (float)MW;
  const float ry = ((float)(idx / MW) + 0.5f) / (float)MH;
  const float x1 = rois[n * 5 + 1], y1 = rois[n * 5 + 2];
  const float x2 = rois[n * 5 + 3], y2 = rois[n * 5 + 4];
  const float px = (x1 + rx * (x2 - x1)) * 0.25f - 0.5f;
  const float py = (y1 + ry * (y2 - y1)) * 0.25f - 0.5f;
  const float x0f = floorf(px), y0f = floorf(py);
  const int x0 = (int)x0f, y0 = (int)y0f;
  const float wx1 = px - x0f, wy1 = py - y0f;
  float out[8] = {};
#pragma unroll
  for (int cy = 0; cy < 2; ++cy) {
    const int yy = y0 + cy;
    const bool vy = (yy >= 0) && (yy <= SHH - 1);
    const int yc = min(max(yy, 0), SHH - 1);
    const float wy = cy ? wy1 : (1.f - wy1);
#pragma unroll
    for (int cx = 0; cx < 2; ++cx) {
      const int xx = x0 + cx;
      const bool vx = (xx >= 0) && (xx <= SWW - 1);
      const int xc = min(max(xx, 0), SWW - 1);
      const float wgt = (vx && vy) ? wy * (cx ? wx1 : (1.f - wx1)) : 0.f;
      const unsigned short* src = sem + ((size_t)yc * SWW + xc) * 256 + c0;
      short8 v = *(const short8*)src;
#pragma unroll
      for (int j = 0; j < 8; ++j) out[j] += wgt * bf2f((unsigned short)v[j]);
    }
  }
  unsigned short* dst = X + ((size_t)n * PP + p) * FCIN + c0;
  short8 o;
#pragma unroll
  for (int j = 0; j < 8; ++j) o[j] = (short)f2bf(out[j]);
  *(short8*)dst = o;
}

// ---------------- K9: 2x bilinear upsample (half-pixel, edge-clamped) --------
__global__ __launch_bounds__(256) void upsample_k(const float* __restrict__ fused,
                                                  float* __restrict__ out2) {
  __shared__ float L[HW];
  const int n = blockIdx.x, c = blockIdx.y;
  const float* src = fused + ((size_t)n * CC + c) * HW;
  for (int i = threadIdx.x; i < HW; i += 256) L[i] = src[i];
  __syncthreads();
  float* dst = out2 + ((size_t)n * CC + c) * 3136;
  for (int i = threadIdx.x; i < 3136; i += 256) {
    const int r = i / 56, q = i % 56;
    const float y = fminf(fmaxf(r * 0.5f - 0.25f, 0.f), 27.f);
    const float x = fminf(fmaxf(q * 0.5f - 0.25f, 0.f), 27.f);
    const int y0 = (int)y, x0 = (int)x;
    const float wy1 = y - (float)y0, wx1 = x - (float)x0;
    const int y1 = min(y0 + 1, 27), x1 = min(x0 + 1, 27);
    const float v00 = L[y0 * 28 + x0], v01 = L[y0 * 28 + x1];
    const float v10 = L[y1 * 28 + x0], v11 = L[y1 * 28 + x1];
    const float v = (1.f - wy1) * ((1.f - wx1) * v00 + wx1 * v01) +
                    wy1 * ((1.f - wx1) * v10 + wx1 * v11);
    dst[i] = fmaxf(v, 0.f);
  }
}

// ---------------- host launcher ----------------------------------------------
extern "C" void kernel_launch(void* const* d_in, const int* in_sizes, int n_in,
                              void* d_out, int out_size, void* d_ws, size_t ws_size,
                              hipStream_t stream) {
  (void)in_sizes; (void)n_in; (void)out_size; (void)ws_size;
  const float* inst   = (const float*)d_in[0];
  const float* semf   = (const float*)d_in[1];
  const float* rois   = (const float*)d_in[2];
  const int*   labels = (const int*)d_in[3];
  const float* w_sem  = (const float*)d_in[5];
  const float* b_sem  = (const float*)d_in[6];
  const float* w_inst = (const float*)d_in[7];
  const float* b_inst = (const float*)d_in[8];
  const float* w_det  = (const float*)d_in[9];
  const float* b_det  = (const float*)d_in[10];
  const float* fc_w0  = (const float*)d_in[11];
  const float* fc_b0  = (const float*)d_in[12];
  const float* fc_w1  = (const float*)d_in[13];
  const float* fc_b1  = (const float*)d_in[14];
  const float* fc_w2  = (const float*)d_in[15];
  const float* fc_b2  = (const float*)d_in[16];
  const float* w_log  = (const float*)d_in[17];
  const float* b_log  = (const float*)d_in[18];
  const float* w_fuse = (const float*)d_in[19];
  const float* b_fuse = (const float*)d_in[20];

  float* out0 = (float*)d_out;
  float* out1 = out0 + NN * HW;
  float* out2 = out0 + 2 * NN * HW;

  // workspace layout (float-offset units, 16B-aligned blocks, no aliasing):
  float* ws = (float*)d_ws;
  float* fused               = ws;                                  // 25,690,112 f
  int*   pidx                = (int*)(ws + 25690112);               //     25,088 i
  unsigned short* semh       = (unsigned short*)(ws + 25715200);    // 10,240,000 h
  unsigned short* semf_t     = (unsigned short*)(ws + 30835200);    // 10,240,000 h
  unsigned short* Xh         = (unsigned short*)(ws + 35955200);    // 10,436,608 h
  unsigned short* Yh         = (unsigned short*)(ws + 41173504);    // 10,436,608 h
  unsigned short* refined_t  = (unsigned short*)(ws + 46391808);    // 25,690,112 h
  unsigned short* wbf        = (unsigned short*)(ws + 59236864);    //    598,016 h
  float* bcat                = ws + 59535872;                       //        160 f

  wconv_k<<<512, 256, 0, stream>>>(w_sem, w_fuse, fc_w0, fc_w1, fc_w2, w_log,
                                   w_inst, w_det, b_inst, b_det, wbf, bcat);
  transpose_bf16_k<<<dim3(625, 4, 1), 256, 0, stream>>>(semf, semf_t, SPIX);
  // sem = relu(semf_t . w_sem^T) -> bf16 [spatial][256]: M=40000,N=256,K=256
  gemm_mfma_k<1, 4><<<dim3(313, 2, 1), 256, 0, stream>>>(
      semf_t, wbf + OW_SEM, b_sem, nullptr, semh, nullptr, SPIX, 256, 256, 256, 256);
  // refined_t = bf16 transpose of inst (needed early: feeds ctail gather)
  transpose_bf16_k<<<dim3(13, 4, NN), 256, 0, stream>>>(inst, refined_t, HW);
  select_maps_k<<<dim3(NN, 4), 256, 0, stream>>>(inst, labels, w_inst, b_inst,
                                                 w_det, b_det, out0, out1);
  topk_k<<<NN, 256, 0, stream>>>(out1, pidx);
  // c_inst/c_det tails: M=25088, N=160, K=256; A rows gathered via pidx
  gemm_mfma_k<2, 5><<<dim3(196, 2, 1), 256, 0, stream>>>(
      refined_t, wbf + OW_CAT, bcat, (float*)Yh, Xh, pidx, NN * PP, 160, 256, 256, 256);
  fine_sample_k<<<dim3(NN, 25), 256, 0, stream>>>(semh, pidx, rois, Xh);
  // MLP: M=25088,N=256,K=416 (bf16 activations at rest)
  gemm_mfma_k<1, 0><<<dim3(196, 2, 1), 256, 0, stream>>>(
      Xh, wbf + OW_FC0, fc_b0, nullptr, Yh, nullptr, NN * PP, 256, FCIN, FCIN, FCIN);
  gemm_mfma_k<1, 0><<<dim3(196, 2, 1), 256, 0, stream>>>(
      Yh, wbf + OW_FC1, fc_b1, nullptr, Xh, nullptr, NN * PP, 256, FCIN, FCIN, FCIN);
  gemm_mfma_k<1, 0><<<dim3(196, 2, 1), 256, 0, stream>>>(
      Xh, wbf + OW_FC2, fc_b2, nullptr, Yh, nullptr, NN * PP, 256, FCIN, FCIN, FCIN);
  // logits scattered into refined_t
  gemm_mfma_k<1, 1><<<dim3(196, 2, 1), 256, 0, stream>>>(
      Yh, wbf + OW_LOG, b_log, nullptr, refined_t, pidx, NN * PP, 256, FCIN, FCIN, FCIN);
  // fuse: per n, D[o][s] = w_fuse[o][:] . refined_t[n][s][:]
  gemm_mfma_k<1, 3><<<dim3(2, 7, NN), 256, 0, stream>>>(
      wbf + OW_FUSE, refined_t, b_fuse, fused, nullptr, nullptr, 256, HW, 256, 256, 256);
  upsample_k<<<dim3(NN, CC), 256, 0, stream>>>(fused, out2);
}

// Round 2
// 845.856 us; speedup vs baseline: 1.4331x; 1.1824x over previous
//
#include <hip/hip_runtime.h>

// ---------------- problem constants ----------------
#define NN   128
#define CC   256
#define MH   28
#define MW   28
#define HW   784        // 28*28
#define KCLS 80
#define PP   196
#define SHH  200
#define SWW  200
#define SPIX 40000      // 200*200
#define FCIN 416        // C + 2K

typedef __attribute__((ext_vector_type(8))) short short8;
typedef __attribute__((ext_vector_type(4))) float f32x4;

__device__ __forceinline__ unsigned short f2bf(float x) {
  unsigned u = __float_as_uint(x);
  unsigned r = (u + 0x7fffu + ((u >> 16) & 1u)) >> 16;
  return (unsigned short)r;
}
__device__ __forceinline__ float bf2f(unsigned short h) {
  return __uint_as_float((unsigned)h << 16);
}

// ---- weight fp32->bf16 convert (concatenated blob) --------------------------
// layout: [w_sem 65536][w_fuse 65536][fc_w0 106496][fc_w1][fc_w2][w_log]
//         [w_cat = w_inst;w_det 40960]
#define OW_SEM  0
#define OW_FUSE 65536
#define OW_FC0  131072
#define OW_FC1  237568
#define OW_FC2  344064
#define OW_LOG  450560
#define OW_CAT  557056
#define OW_TOT  598016
__global__ void wconv_k(const float* __restrict__ wsem, const float* __restrict__ wfuse,
                        const float* __restrict__ w0, const float* __restrict__ w1,
                        const float* __restrict__ w2, const float* __restrict__ wlog,
                        const float* __restrict__ wi, const float* __restrict__ wd,
                        const float* __restrict__ bi, const float* __restrict__ bd,
                        unsigned short* __restrict__ out, float* __restrict__ bcat) {
  const int tid0 = blockIdx.x * blockDim.x + threadIdx.x;
  if (tid0 < KCLS) bcat[tid0] = bi[tid0];
  else if (tid0 < 2 * KCLS) bcat[tid0] = bd[tid0 - KCLS];
  for (int i = tid0; i < OW_TOT; i += gridDim.x * blockDim.x) {
    float v;
    if (i < OW_FUSE) v = wsem[i];
    else if (i < OW_FC0) v = wfuse[i - OW_FUSE];
    else if (i < OW_FC1) v = w0[i - OW_FC0];
    else if (i < OW_FC2) v = w1[i - OW_FC1];
    else if (i < OW_LOG) v = w2[i - OW_FC2];
    else if (i < OW_CAT) v = wlog[i - OW_LOG];
    else if (i < OW_CAT + KCLS * 256) v = wi[i - OW_CAT];
    else v = wd[i - OW_CAT - KCLS * 256];
    out[i] = f2bf(v);
  }
}

// ---- transpose+convert: src fp32 [256][P] (c-major) -> dst bf16 [P][256] ----
__global__ __launch_bounds__(256) void transpose_bf16_k(
    const float* __restrict__ src, unsigned short* __restrict__ dst, int P) {
  __shared__ float T[64][69];
  const int t = threadIdx.x;
  src += (size_t)blockIdx.z * 256 * P;
  dst += (size_t)blockIdx.z * P * 256;
  const int p0 = blockIdx.x * 64, c0 = blockIdx.y * 64;
#pragma unroll
  for (int it = 0; it < 16; ++it) {
    int idx = it * 256 + t, c = idx >> 6, p = idx & 63;
    T[c][p] = (p0 + p < P) ? src[(size_t)(c0 + c) * P + p0 + p] : 0.f;
  }
  __syncthreads();
#pragma unroll
  for (int it = 0; it < 16; ++it) {
    int idx = it * 256 + t, p = idx >> 6, c = idx & 63;
    if (p0 + p < P) dst[(size_t)(p0 + p) * 256 + c0 + c] = f2bf(T[c][p]);
  }
}

// ---- generic MFMA bf16 GEMM: D[m][n] = A[m][:] . B[n][:] (both k-innermost) -
// block tile 128x128, 4 waves, wave tile 64x64 (4x4 frags of 16x16x32).
// EPI:  3 = fuse (relu, fp32 out [m*HW + n] per batch z, bias[m])
//       4 = sem  (relu, bf16 out [m][256], bias[n])
template <int ASRC, int EPI>
__global__ __launch_bounds__(256) void gemm_mfma_k(
    const void* __restrict__ Ap, const unsigned short* __restrict__ Bmat,
    const float* __restrict__ bias, float* __restrict__ outf,
    unsigned short* __restrict__ outh, const int* __restrict__ pidx,
    int M, int N, int K, int lda, int ldb) {
  __shared__ __align__(16) unsigned short Abuf[128 * 40];
  __shared__ __align__(16) unsigned short Bbuf[128 * 40];
  const int t = threadIdx.x;
  const int m0 = blockIdx.x * 128, n0 = blockIdx.y * 128;
  if (EPI == 3) {
    Bmat += (size_t)blockIdx.z * HW * 256;
    outf += (size_t)blockIdx.z * CC * HW;
  }
  const unsigned short* Ah = (const unsigned short*)Ap;
  const int wave = t >> 6, lane = t & 63, lq = lane >> 4, lr = lane & 15;
  const int msub = (wave & 1) * 64, nsub = (wave >> 1) * 64;
  f32x4 acc[4][4] = {};
  for (int kc = 0; kc < K; kc += 32) {
#pragma unroll
    for (int it = 0; it < 4; ++it) {
      const int idx = it * 256 + t, r = idx >> 3, jg = idx & 7;
      const int gm = m0 + r;
      ushort4 h = make_ushort4(0, 0, 0, 0);
      if (gm < M) h = *(const ushort4*)&Ah[(size_t)gm * lda + kc + jg * 4];
      *(ushort4*)&Abuf[r * 40 + jg * 4] = h;
    }
#pragma unroll
    for (int it = 0; it < 4; ++it) {
      const int idx = it * 256 + t, r = idx >> 3, jg = idx & 7;
      const int gn = n0 + r;
      ushort4 h = make_ushort4(0, 0, 0, 0);
      if (gn < N) h = *(const ushort4*)&Bmat[(size_t)gn * ldb + kc + jg * 4];
      *(ushort4*)&Bbuf[r * 40 + jg * 4] = h;
    }
    __syncthreads();
    short8 af[4], bfr[4];
#pragma unroll
    for (int i = 0; i < 4; ++i)
      af[i] = *(const short8*)&Abuf[(msub + i * 16 + lr) * 40 + lq * 8];
#pragma unroll
    for (int f = 0; f < 4; ++f)
      bfr[f] = *(const short8*)&Bbuf[(nsub + f * 16 + lr) * 40 + lq * 8];
#pragma unroll
    for (int i = 0; i < 4; ++i)
#pragma unroll
      for (int f = 0; f < 4; ++f)
        acc[i][f] = __builtin_amdgcn_mfma_f32_16x16x32_bf16(af[i], bfr[f],
                                                            acc[i][f], 0, 0, 0);
    __syncthreads();
  }
  // epilogue: C/D layout col=lane&15, row=lq*4+reg  [verified m89/m91]
#pragma unroll
  for (int i = 0; i < 4; ++i) {
#pragma unroll
    for (int r = 0; r < 4; ++r) {
      const int gm = m0 + msub + i * 16 + lq * 4 + r;
      if (EPI == 3) {  // m = out channel, n = spatial
        const float bb = bias[gm];
#pragma unroll
        for (int f = 0; f < 4; ++f) {
          const int gs = n0 + nsub + f * 16 + lr;
          if (gs < N) outf[(size_t)gm * HW + gs] = fmaxf(acc[i][f][r] + bb, 0.f);
        }
      } else if (EPI == 4) {
        if (gm < M) {
#pragma unroll
          for (int f = 0; f < 4; ++f) {
            const int go = n0 + nsub + f * 16 + lr;
            outh[(size_t)gm * 256 + go] = f2bf(fmaxf(acc[i][f][r] + bias[go], 0.f));
          }
        }
      }
    }
  }
}

// ---------------- persistent fused point-branch kernel -----------------------
// One block = 64 point-rows. X[64][416] bf16 lives in LDS across:
//   head (bilinear sem sample) -> ctail MFMA -> 3x FC MFMA -> logits scatter.
// Weights read direct from global (L2-hot); no B-staging, barriers only
// between layers. MFMA order identical to the discrete GEMMs (bitwise-equal).
#define XRS 424  // X row stride in shorts (416+8 pad; 212 dw % 32 = 20 -> spread)
__global__ __launch_bounds__(256) void fused_point_k(
    const unsigned short* __restrict__ semh,
    unsigned short* __restrict__ refined_t,
    const int* __restrict__ pidx, const float* __restrict__ rois,
    const unsigned short* __restrict__ wbf, const float* __restrict__ bcat,
    const float* __restrict__ fb0, const float* __restrict__ fb1,
    const float* __restrict__ fb2, const float* __restrict__ bl) {
  __shared__ __align__(16) unsigned short X[64 * XRS];
  __shared__ int rowoff[64];
  __shared__ float pxs[64], pys[64];
  const int t = threadIdx.x;
  const int gm0 = blockIdx.x * 64;
  const int lane = t & 63, wave = t >> 6, lq = lane >> 4, lr = lane & 15;
  // ---- phase 0: per-row scatter offsets + ROI pixel coords ----
  if (t < 64) {
    const int gm = gm0 + t;
    const int n = gm / PP;
    const int si = pidx[gm];
    rowoff[t] = (n * HW + si) * 256;
    const float rx = ((float)(si % MW) + 0.5f) / (float)MW;
    const float ry = ((float)(si / MW) + 0.5f) / (float)MH;
    const float x1 = rois[n * 5 + 1], y1 = rois[n * 5 + 2];
    const float x2 = rois[n * 5 + 3], y2 = rois[n * 5 + 4];
    pxs[t] = (x1 + rx * (x2 - x1)) * 0.25f - 0.5f;
    pys[t] = (y1 + ry * (y2 - y1)) * 0.25f - 0.5f;
  }
  __syncthreads();
  // ---- phase 1: bilinear head -> X[:, 0..255] ----
  {
    const int c0 = (t & 31) * 8;
    const int rbase = t >> 5;
#pragma unroll
    for (int it = 0; it < 8; ++it) {
      const int r = it * 8 + rbase;
      const float px = pxs[r], py = pys[r];
      const float x0f = floorf(px), y0f = floorf(py);
      const int x0 = (int)x0f, y0 = (int)y0f;
      const float wx1 = px - x0f, wy1 = py - y0f;
      float out[8] = {};
#pragma unroll
      for (int cy = 0; cy < 2; ++cy) {
        const int yy = y0 + cy;
        const bool vy = (yy >= 0) && (yy <= SHH - 1);
        const int yc = min(max(yy, 0), SHH - 1);
        const float wy = cy ? wy1 : (1.f - wy1);
#pragma unroll
        for (int cx = 0; cx < 2; ++cx) {
          const int xx = x0 + cx;
          const bool vx = (xx >= 0) && (xx <= SWW - 1);
          const int xc = min(max(xx, 0), SWW - 1);
          const float wgt = (vx && vy) ? wy * (cx ? wx1 : (1.f - wx1)) : 0.f;
          const unsigned short* src = semh + ((size_t)yc * SWW + xc) * 256 + c0;
          short8 v = *(const short8*)src;
#pragma unroll
          for (int j = 0; j < 8; ++j) out[j] += wgt * bf2f((unsigned short)v[j]);
        }
      }
      short8 o;
#pragma unroll
      for (int j = 0; j < 8; ++j) o[j] = (short)f2bf(out[j]);
      *(short8*)&X[r * XRS + c0] = o;
    }
  }
  // ---- phase 2: ctail = G(64x256, gathered) . Wcat^T(160x256) -> X[:,256..415]
  // waves split M: wave owns rows [wave*16, wave*16+16), 10 n-frags (160 exact)
  {
    const int grow = rowoff[wave * 16 + lr];  // A-frag row (by lr)
    const unsigned short* Wc = wbf + OW_CAT;
    f32x4 acc[10] = {};
    for (int kc = 0; kc < 256; kc += 32) {
      const short8 a = *(const short8*)&refined_t[(size_t)grow + kc + lq * 8];
#pragma unroll
      for (int f = 0; f < 10; ++f) {
        const short8 b = *(const short8*)&Wc[(size_t)(f * 16 + lr) * 256 + kc + lq * 8];
        acc[f] = __builtin_amdgcn_mfma_f32_16x16x32_bf16(a, b, acc[f], 0, 0, 0);
      }
    }
#pragma unroll
    for (int f = 0; f < 10; ++f) {
      const int col = 256 + f * 16 + lr;
      const float bb = bcat[f * 16 + lr];
#pragma unroll
      for (int r = 0; r < 4; ++r) {
        const int row = wave * 16 + lq * 4 + r;
        X[row * XRS + col] = f2bf(acc[f][r] + bb);
      }
    }
  }
  __syncthreads();
  // ---- phases 3-6: FC0, FC1, FC2 (relu -> X[:,0..255]), logits (scatter) ----
  const int n0w = wave * 64;
  for (int layer = 0; layer < 4; ++layer) {
    const unsigned short* Wl = wbf + OW_FC0 + layer * 106496;
    const float* bias = (layer == 0) ? fb0 : (layer == 1) ? fb1
                        : (layer == 2) ? fb2 : bl;
    f32x4 acc[4][4] = {};
#pragma unroll 2
    for (int kc = 0; kc < FCIN; kc += 32) {
      short8 af[4], bfr[4];
#pragma unroll
      for (int i = 0; i < 4; ++i)
        af[i] = *(const short8*)&X[(i * 16 + lr) * XRS + kc + lq * 8];
#pragma unroll
      for (int f = 0; f < 4; ++f)
        bfr[f] = *(const short8*)&Wl[(size_t)(n0w + f * 16 + lr) * FCIN + kc + lq * 8];
#pragma unroll
      for (int i = 0; i < 4; ++i)
#pragma unroll
        for (int f = 0; f < 4; ++f)
          acc[i][f] = __builtin_amdgcn_mfma_f32_16x16x32_bf16(af[i], bfr[f],
                                                              acc[i][f], 0, 0, 0);
    }
    __syncthreads();  // all X reads of this layer complete
    if (layer < 3) {
#pragma unroll
      for (int i = 0; i < 4; ++i)
#pragma unroll
        for (int r = 0; r < 4; ++r) {
          const int row = i * 16 + lq * 4 + r;
#pragma unroll
          for (int f = 0; f < 4; ++f) {
            const int col = n0w + f * 16 + lr;
            X[row * XRS + col] = f2bf(fmaxf(acc[i][f][r] + bias[col], 0.f));
          }
        }
    } else {
#pragma unroll
      for (int i = 0; i < 4; ++i)
#pragma unroll
        for (int r = 0; r < 4; ++r) {
          const int row = i * 16 + lq * 4 + r;
          unsigned short* dst = refined_t + (size_t)rowoff[row];
#pragma unroll
          for (int f = 0; f < 4; ++f) {
            const int col = n0w + f * 16 + lr;
            dst[col] = f2bf(acc[i][f][r] + bias[col]);
          }
        }
    }
    __syncthreads();  // X writes visible before next layer reads
  }
}

// ---------------- K2: class-selected inst/det maps (outputs 0 & 1) ----------
__global__ __launch_bounds__(256) void select_maps_k(
    const float* __restrict__ inst, const int* __restrict__ labels,
    const float* __restrict__ w_inst, const float* __restrict__ b_inst,
    const float* __restrict__ w_det, const float* __restrict__ b_det,
    float* __restrict__ out0, float* __restrict__ out1) {
  const int n = blockIdx.x;
  const int s = blockIdx.y * 196 + threadIdx.x;
  if (threadIdx.x >= 196) return;
  const int lab = labels[n];
  const float* fi = inst + (size_t)n * CC * HW + s;
  const float* wi = w_inst + lab * 256;
  const float* wd = w_det + lab * 256;
  double ai = 0.0, ad = 0.0;
  for (int c = 0; c < 256; ++c) {
    const float v = fi[c * HW];
    ai += (double)v * (double)wi[c];
    ad += (double)v * (double)wd[c];
  }
  out0[n * HW + s] = (float)(ai + (double)b_inst[lab]);
  out1[n * HW + s] = (float)(ad + (double)b_det[lab]);
}

// ---------------- K3: per-n top-196 of 784 via bitonic sort ------------------
__global__ __launch_bounds__(256) void topk_k(const float* __restrict__ det,
                                              int* __restrict__ pidx) {
  __shared__ unsigned long long keys[1024];
  const int n = blockIdx.x;
  for (int i = threadIdx.x; i < 1024; i += 256) {
    unsigned long long kk = 0ull;
    if (i < HW) {
      unsigned u = __float_as_uint(det[n * HW + i]);
      u = (u & 0x80000000u) ? ~u : (u | 0x80000000u);
      kk = ((unsigned long long)u << 32) | (unsigned)(1023 - i);
    }
    keys[i] = kk;
  }
  __syncthreads();
  for (int k = 2; k <= 1024; k <<= 1) {
    for (int j = k >> 1; j > 0; j >>= 1) {
      for (int i = threadIdx.x; i < 1024; i += 256) {
        const int l = i ^ j;
        if (l > i) {
          const bool up = ((i & k) == 0);
          unsigned long long a = keys[i], bb = keys[l];
          if ((a > bb) == up) { keys[i] = bb; keys[l] = a; }
        }
      }
      __syncthreads();
    }
  }
  for (int r = threadIdx.x; r < PP; r += 256)
    pidx[n * PP + r] = 1023 - (int)(keys[828 + r] & 1023ull);
}

// ---------------- K9: 2x bilinear upsample (half-pixel, edge-clamped) --------
__global__ __launch_bounds__(256) void upsample_k(const float* __restrict__ fused,
                                                  float* __restrict__ out2) {
  __shared__ float L[HW];
  const int n = blockIdx.x, c = blockIdx.y;
  const float* src = fused + ((size_t)n * CC + c) * HW;
  for (int i = threadIdx.x; i < HW; i += 256) L[i] = src[i];
  __syncthreads();
  float* dst = out2 + ((size_t)n * CC + c) * 3136;
  for (int i = threadIdx.x; i < 3136; i += 256) {
    const int r = i / 56, q = i % 56;
    const float y = fminf(fmaxf(r * 0.5f - 0.25f, 0.f), 27.f);
    const float x = fminf(fmaxf(q * 0.5f - 0.25f, 0.f), 27.f);
    const int y0 = (int)y, x0 = (int)x;
    const float wy1 = y - (float)y0, wx1 = x - (float)x0;
    const int y1 = min(y0 + 1, 27), x1 = min(x0 + 1, 27);
    const float v00 = L[y0 * 28 + x0], v01 = L[y0 * 28 + x1];
    const float v10 = L[y1 * 28 + x0], v11 = L[y1 * 28 + x1];
    const float v = (1.f - wy1) * ((1.f - wx1) * v00 + wx1 * v01) +
                    wy1 * ((1.f - wx1) * v10 + wx1 * v11);
    dst[i] = fmaxf(v, 0.f);
  }
}

// ---------------- host launcher ----------------------------------------------
extern "C" void kernel_launch(void* const* d_in, const int* in_sizes, int n_in,
                              void* d_out, int out_size, void* d_ws, size_t ws_size,
                              hipStream_t stream) {
  (void)in_sizes; (void)n_in; (void)out_size; (void)ws_size;
  const float* inst   = (const float*)d_in[0];
  const float* semf   = (const float*)d_in[1];
  const float* rois   = (const float*)d_in[2];
  const int*   labels = (const int*)d_in[3];
  const float* w_sem  = (const float*)d_in[5];
  const float* b_sem  = (const float*)d_in[6];
  const float* w_inst = (const float*)d_in[7];
  const float* b_inst = (const float*)d_in[8];
  const float* w_det  = (const float*)d_in[9];
  const float* b_det  = (const float*)d_in[10];
  const float* fc_w0  = (const float*)d_in[11];
  const float* fc_b0  = (const float*)d_in[12];
  const float* fc_w1  = (const float*)d_in[13];
  const float* fc_b1  = (const float*)d_in[14];
  const float* fc_w2  = (const float*)d_in[15];
  const float* fc_b2  = (const float*)d_in[16];
  const float* w_log  = (const float*)d_in[17];
  const float* b_log  = (const float*)d_in[18];
  const float* w_fuse = (const float*)d_in[19];
  const float* b_fuse = (const float*)d_in[20];

  float* out0 = (float*)d_out;
  float* out1 = out0 + NN * HW;
  float* out2 = out0 + 2 * NN * HW;

  // workspace layout (float-offset units, 16B-aligned blocks, no aliasing):
  float* ws = (float*)d_ws;
  float* fused               = ws;                                  // 25,690,112 f
  int*   pidx                = (int*)(ws + 25690112);               //     25,088 i
  unsigned short* semh       = (unsigned short*)(ws + 25715200);    // 10,240,000 h
  unsigned short* semf_t     = (unsigned short*)(ws + 30835200);    // 10,240,000 h
  unsigned short* refined_t  = (unsigned short*)(ws + 35955200);    // 25,690,112 h
  unsigned short* wbf        = (unsigned short*)(ws + 48800256);    //    598,016 h
  float* bcat                = ws + 49099264;                       //        160 f

  wconv_k<<<512, 256, 0, stream>>>(w_sem, w_fuse, fc_w0, fc_w1, fc_w2, w_log,
                                   w_inst, w_det, b_inst, b_det, wbf, bcat);
  transpose_bf16_k<<<dim3(625, 4, 1), 256, 0, stream>>>(semf, semf_t, SPIX);
  // sem = relu(semf_t . w_sem^T) -> bf16 [spatial][256]: M=40000,N=256,K=256
  gemm_mfma_k<1, 4><<<dim3(313, 2, 1), 256, 0, stream>>>(
      semf_t, wbf + OW_SEM, b_sem, nullptr, semh, nullptr, SPIX, 256, 256, 256, 256);
  // refined_t = bf16 transpose of inst (feeds ctail gather + fuse GEMM)
  transpose_bf16_k<<<dim3(13, 4, NN), 256, 0, stream>>>(inst, refined_t, HW);
  select_maps_k<<<dim3(NN, 4), 256, 0, stream>>>(inst, labels, w_inst, b_inst,
                                                 w_det, b_det, out0, out1);
  topk_k<<<NN, 256, 0, stream>>>(out1, pidx);
  // fused point branch: head + ctail + 3xFC + logits scatter (392 blocks)
  fused_point_k<<<392, 256, 0, stream>>>(semh, refined_t, pidx, rois, wbf, bcat,
                                         fc_b0, fc_b1, fc_b2, b_log);
  // fuse: per n, D[o][s] = w_fuse[o][:] . refined_t[n][s][:]
  gemm_mfma_k<1, 3><<<dim3(2, 7, NN), 256, 0, stream>>>(
      wbf + OW_FUSE, refined_t, b_fuse, fused, nullptr, nullptr, 256, HW, 256, 256, 256);
  upsample_k<<<dim3(NN, CC), 256, 0, stream>>>(fused, out2);
}

// Round 3
// 827.417 us; speedup vs baseline: 1.4650x; 1.0223x over previous
//
#include <hip/hip_runtime.h>

// ---------------- problem constants ----------------
#define NN   128
#define CC   256
#define MH   28
#define MW   28
#define HW   784        // 28*28
#define KCLS 80
#define PP   196
#define SHH  200
#define SWW  200
#define SPIX 40000      // 200*200
#define FCIN 416        // C + 2K

typedef __attribute__((ext_vector_type(8))) short short8;
typedef __attribute__((ext_vector_type(4))) float f32x4;

__device__ __forceinline__ unsigned short f2bf(float x) {
  unsigned u = __float_as_uint(x);
  unsigned r = (u + 0x7fffu + ((u >> 16) & 1u)) >> 16;
  return (unsigned short)r;
}
__device__ __forceinline__ float bf2f(unsigned short h) {
  return __uint_as_float((unsigned)h << 16);
}

// ---- weight bf16 blob layout ----
#define OW_SEM  0
#define OW_FUSE 65536
#define OW_FC0  131072
#define OW_FC1  237568
#define OW_FC2  344064
#define OW_LOG  450560
#define OW_CAT  557056
#define OW_TOT  598016

// ================= megaA: wconv + sem-transpose + inst-transpose(+dots) =====
// blocks [0,2500): semf fp32 [256][40000] -> semf_t bf16 [40000][256]
// blocks [2500,9156): inst fp32 [n][256][784] -> refined_t bf16 [n][784][256]
//                     + fp64 partial dots vs w_inst/w_det[lab] -> Pb0/Pb1
// blocks [9156,9412): weight fp32->bf16 blob + bcat
#define GA_SEMT 2500
#define GA_INST 9156
#define GA_TOT  9412
__global__ __launch_bounds__(256) void megaA_k(
    const float* __restrict__ semf, unsigned short* __restrict__ semf_t,
    const float* __restrict__ inst, unsigned short* __restrict__ refined_t,
    const int* __restrict__ labels,
    const float* __restrict__ w_inst, const float* __restrict__ w_det,
    double* __restrict__ Pb0, double* __restrict__ Pb1,
    const float* __restrict__ wsem, const float* __restrict__ wfuse,
    const float* __restrict__ w0, const float* __restrict__ w1,
    const float* __restrict__ w2, const float* __restrict__ wlog,
    const float* __restrict__ bi, const float* __restrict__ bd,
    unsigned short* __restrict__ wbf, float* __restrict__ bcat) {
  __shared__ float T[64][69];
  __shared__ double Dbi[4][65], Dbd[4][65];
  const int bid = blockIdx.x;
  const int t = threadIdx.x;
  if (bid < GA_INST) {
    const bool isInst = (bid >= GA_SEMT);
    int x, y, n, P;
    const float* src;
    unsigned short* dst;
    if (!isInst) {
      x = bid % 625; y = bid / 625; n = 0; P = SPIX;
      src = semf; dst = semf_t;
    } else {
      const int b = bid - GA_SEMT;
      n = b / 52; const int rr = b % 52; x = rr % 13; y = rr / 13; P = HW;
      src = inst + (size_t)n * CC * HW;
      dst = refined_t + (size_t)n * HW * 256;
    }
    const int p0 = x * 64, c0 = y * 64;
#pragma unroll
    for (int it = 0; it < 16; ++it) {
      int idx = it * 256 + t, c = idx >> 6, p = idx & 63;
      T[c][p] = (p0 + p < P) ? src[(size_t)(c0 + c) * P + p0 + p] : 0.f;
    }
    __syncthreads();
#pragma unroll
    for (int it = 0; it < 16; ++it) {
      int idx = it * 256 + t, p = idx >> 6, c = idx & 63;
      if (p0 + p < P) dst[(size_t)(p0 + p) * 256 + c0 + c] = f2bf(T[c][p]);
    }
    if (isInst) {
      const int lab = labels[n];
      const float* wi = w_inst + lab * 256 + c0;
      const float* wd = w_det + lab * 256 + c0;
      const int q = t >> 6, p = t & 63;
      double si = 0.0, sd = 0.0;
#pragma unroll
      for (int j = 0; j < 16; ++j) {
        const int c = q * 16 + j;
        const double v = (double)T[c][p];
        si += v * (double)wi[c];
        sd += v * (double)wd[c];
      }
      Dbi[q][p] = si; Dbd[q][p] = sd;
      __syncthreads();
      if (t < 64 && p0 + t < HW) {
        const double fi = ((Dbi[0][t] + Dbi[1][t]) + Dbi[2][t]) + Dbi[3][t];
        const double fd = ((Dbd[0][t] + Dbd[1][t]) + Dbd[2][t]) + Dbd[3][t];
        const size_t o = ((size_t)n * 4 + y) * HW + p0 + t;
        Pb0[o] = fi; Pb1[o] = fd;
      }
    }
  } else {
    // weight convert
    const int tid0 = (bid - GA_INST) * 256 + t;
    if (tid0 < KCLS) bcat[tid0] = bi[tid0];
    else if (tid0 < 2 * KCLS) bcat[tid0] = bd[tid0 - KCLS];
    for (int i = tid0; i < OW_TOT; i += 256 * 256) {
      float v;
      if (i < OW_FUSE) v = wsem[i];
      else if (i < OW_FC0) v = wfuse[i - OW_FUSE];
      else if (i < OW_FC1) v = w0[i - OW_FC0];
      else if (i < OW_FC2) v = w1[i - OW_FC1];
      else if (i < OW_LOG) v = w2[i - OW_FC2];
      else if (i < OW_CAT) v = wlog[i - OW_LOG];
      else if (i < OW_CAT + KCLS * 256) v = w_inst[i - OW_CAT];
      else v = w_det[i - OW_CAT - KCLS * 256];
      wbf[i] = f2bf(v);
    }
  }
}

// ================= megaB: sem GEMM (626 blocks) + topk finalize (128) =======
// gemm: semh[s][o] = relu(semf_t[s][:].w_sem[o][:] + b_sem[o]), M=40000,N=256,K=256
// topk: fixed-order fp64 partial sum -> out0/out1, bitonic top-196 -> pidx
#define GB_GEMM 626
#define GB_TOT  754
__global__ __launch_bounds__(256) void megaB_k(
    const unsigned short* __restrict__ semf_t, const unsigned short* __restrict__ wbf,
    const float* __restrict__ b_sem, unsigned short* __restrict__ semh,
    const double* __restrict__ Pb0, const double* __restrict__ Pb1,
    const int* __restrict__ labels,
    const float* __restrict__ b_inst, const float* __restrict__ b_det,
    float* __restrict__ out0, float* __restrict__ out1, int* __restrict__ pidx) {
  __shared__ __align__(16) unsigned char sm[20480];
  const int bid = blockIdx.x, t = threadIdx.x;
  if (bid < GB_GEMM) {
    unsigned short* Abuf = (unsigned short*)sm;             // 128*40 shorts
    unsigned short* Bbuf = (unsigned short*)(sm + 10240);   // 128*40 shorts
    const int m0 = (bid % 313) * 128, n0 = (bid / 313) * 128;
    const unsigned short* Bw = wbf + OW_SEM;
    const int lane = t & 63, wave = t >> 6, lq = lane >> 4, lr = lane & 15;
    const int msub = (wave & 1) * 64, nsub = (wave >> 1) * 64;
    f32x4 acc[4][4] = {};
    for (int kc = 0; kc < 256; kc += 32) {
#pragma unroll
      for (int it = 0; it < 4; ++it) {
        const int idx = it * 256 + t, r = idx >> 3, jg = idx & 7;
        const int gm = m0 + r;
        ushort4 h = make_ushort4(0, 0, 0, 0);
        if (gm < SPIX) h = *(const ushort4*)&semf_t[(size_t)gm * 256 + kc + jg * 4];
        *(ushort4*)&Abuf[r * 40 + jg * 4] = h;
      }
#pragma unroll
      for (int it = 0; it < 4; ++it) {
        const int idx = it * 256 + t, r = idx >> 3, jg = idx & 7;
        const int gn = n0 + r;
        ushort4 h = make_ushort4(0, 0, 0, 0);
        if (gn < 256) h = *(const ushort4*)&Bw[(size_t)gn * 256 + kc + jg * 4];
        *(ushort4*)&Bbuf[r * 40 + jg * 4] = h;
      }
      __syncthreads();
      short8 af[4], bfr[4];
#pragma unroll
      for (int i = 0; i < 4; ++i)
        af[i] = *(const short8*)&Abuf[(msub + i * 16 + lr) * 40 + lq * 8];
#pragma unroll
      for (int f = 0; f < 4; ++f)
        bfr[f] = *(const short8*)&Bbuf[(nsub + f * 16 + lr) * 40 + lq * 8];
#pragma unroll
      for (int i = 0; i < 4; ++i)
#pragma unroll
        for (int f = 0; f < 4; ++f)
          acc[i][f] = __builtin_amdgcn_mfma_f32_16x16x32_bf16(af[i], bfr[f],
                                                              acc[i][f], 0, 0, 0);
      __syncthreads();
    }
#pragma unroll
    for (int i = 0; i < 4; ++i)
#pragma unroll
      for (int r = 0; r < 4; ++r) {
        const int gm = m0 + msub + i * 16 + lq * 4 + r;
        if (gm < SPIX) {
#pragma unroll
          for (int f = 0; f < 4; ++f) {
            const int go = n0 + nsub + f * 16 + lr;
            semh[(size_t)gm * 256 + go] = f2bf(fmaxf(acc[i][f][r] + b_sem[go], 0.f));
          }
        }
      }
  } else {
    unsigned long long* keys = (unsigned long long*)sm;     // 1024 * 8B
    const int n = bid - GB_GEMM;
    const int lab = labels[n];
    const double bdi = (double)b_inst[lab], bdd = (double)b_det[lab];
    for (int i = t; i < 1024; i += 256) {
      unsigned long long kk = 0ull;
      if (i < HW) {
        const size_t base = (size_t)n * 4 * HW + i;
        const double fi = ((Pb0[base] + Pb0[base + HW]) + Pb0[base + 2 * HW]) + Pb0[base + 3 * HW];
        const double fd = ((Pb1[base] + Pb1[base + HW]) + Pb1[base + 2 * HW]) + Pb1[base + 3 * HW];
        const float vi = (float)(fi + bdi);
        const float vd = (float)(fd + bdd);
        out0[n * HW + i] = vi;
        out1[n * HW + i] = vd;
        unsigned u = __float_as_uint(vd);
        u = (u & 0x80000000u) ? ~u : (u | 0x80000000u);
        kk = ((unsigned long long)u << 32) | (unsigned)(1023 - i);
      }
      keys[i] = kk;
    }
    __syncthreads();
    for (int k = 2; k <= 1024; k <<= 1) {
      for (int j = k >> 1; j > 0; j >>= 1) {
        for (int i = t; i < 1024; i += 256) {
          const int l = i ^ j;
          if (l > i) {
            const bool up = ((i & k) == 0);
            unsigned long long a = keys[i], bb = keys[l];
            if ((a > bb) == up) { keys[i] = bb; keys[l] = a; }
          }
        }
        __syncthreads();
      }
    }
    for (int r = t; r < PP; r += 256)
      pidx[n * PP + r] = 1023 - (int)(keys[828 + r] & 1023ull);
  }
}

// ================= persistent fused point-branch kernel =====================
#define XRS 424
__global__ __launch_bounds__(256) void fused_point_k(
    const unsigned short* __restrict__ semh,
    unsigned short* __restrict__ refined_t,
    const int* __restrict__ pidx, const float* __restrict__ rois,
    const unsigned short* __restrict__ wbf, const float* __restrict__ bcat,
    const float* __restrict__ fb0, const float* __restrict__ fb1,
    const float* __restrict__ fb2, const float* __restrict__ bl) {
  __shared__ __align__(16) unsigned short X[64 * XRS];
  __shared__ int rowoff[64];
  __shared__ float pxs[64], pys[64];
  const int t = threadIdx.x;
  const int gm0 = blockIdx.x * 64;
  const int lane = t & 63, wave = t >> 6, lq = lane >> 4, lr = lane & 15;
  if (t < 64) {
    const int gm = gm0 + t;
    const int n = gm / PP;
    const int si = pidx[gm];
    rowoff[t] = (n * HW + si) * 256;
    const float rx = ((float)(si % MW) + 0.5f) / (float)MW;
    const float ry = ((float)(si / MW) + 0.5f) / (float)MH;
    const float x1 = rois[n * 5 + 1], y1 = rois[n * 5 + 2];
    const float x2 = rois[n * 5 + 3], y2 = rois[n * 5 + 4];
    pxs[t] = (x1 + rx * (x2 - x1)) * 0.25f - 0.5f;
    pys[t] = (y1 + ry * (y2 - y1)) * 0.25f - 0.5f;
  }
  __syncthreads();
  // bilinear head -> X[:,0..255]
  {
    const int c0 = (t & 31) * 8;
    const int rbase = t >> 5;
#pragma unroll
    for (int it = 0; it < 8; ++it) {
      const int r = it * 8 + rbase;
      const float px = pxs[r], py = pys[r];
      const float x0f = floorf(px), y0f = floorf(py);
      const int x0 = (int)x0f, y0 = (int)y0f;
      const float wx1 = px - x0f, wy1 = py - y0f;
      float out[8] = {};
#pragma unroll
      for (int cy = 0; cy < 2; ++cy) {
        const int yy = y0 + cy;
        const bool vy = (yy >= 0) && (yy <= SHH - 1);
        const int yc = min(max(yy, 0), SHH - 1);
        const float wy = cy ? wy1 : (1.f - wy1);
#pragma unroll
        for (int cx = 0; cx < 2; ++cx) {
          const int xx = x0 + cx;
          const bool vx = (xx >= 0) && (xx <= SWW - 1);
          const int xc = min(max(xx, 0), SWW - 1);
          const float wgt = (vx && vy) ? wy * (cx ? wx1 : (1.f - wx1)) : 0.f;
          const unsigned short* src = semh + ((size_t)yc * SWW + xc) * 256 + c0;
          short8 v = *(const short8*)src;
#pragma unroll
          for (int j = 0; j < 8; ++j) out[j] += wgt * bf2f((unsigned short)v[j]);
        }
      }
      short8 o;
#pragma unroll
      for (int j = 0; j < 8; ++j) o[j] = (short)f2bf(out[j]);
      *(short8*)&X[r * XRS + c0] = o;
    }
  }
  // ctail -> X[:,256..415]
  {
    const int grow = rowoff[wave * 16 + lr];
    const unsigned short* Wc = wbf + OW_CAT;
    f32x4 acc[10] = {};
    for (int kc = 0; kc < 256; kc += 32) {
      const short8 a = *(const short8*)&refined_t[(size_t)grow + kc + lq * 8];
#pragma unroll
      for (int f = 0; f < 10; ++f) {
        const short8 b = *(const short8*)&Wc[(size_t)(f * 16 + lr) * 256 + kc + lq * 8];
        acc[f] = __builtin_amdgcn_mfma_f32_16x16x32_bf16(a, b, acc[f], 0, 0, 0);
      }
    }
#pragma unroll
    for (int f = 0; f < 10; ++f) {
      const int col = 256 + f * 16 + lr;
      const float bb = bcat[f * 16 + lr];
#pragma unroll
      for (int r = 0; r < 4; ++r) {
        const int row = wave * 16 + lq * 4 + r;
        X[row * XRS + col] = f2bf(acc[f][r] + bb);
      }
    }
  }
  __syncthreads();
  // FC0, FC1, FC2 (relu -> X[:,0..255]), logits (scatter to refined_t)
  const int n0w = wave * 64;
  for (int layer = 0; layer < 4; ++layer) {
    const unsigned short* Wl = wbf + OW_FC0 + layer * 106496;
    const float* bias = (layer == 0) ? fb0 : (layer == 1) ? fb1
                        : (layer == 2) ? fb2 : bl;
    f32x4 acc[4][4] = {};
#pragma unroll 2
    for (int kc = 0; kc < FCIN; kc += 32) {
      short8 af[4], bfr[4];
#pragma unroll
      for (int i = 0; i < 4; ++i)
        af[i] = *(const short8*)&X[(i * 16 + lr) * XRS + kc + lq * 8];
#pragma unroll
      for (int f = 0; f < 4; ++f)
        bfr[f] = *(const short8*)&Wl[(size_t)(n0w + f * 16 + lr) * FCIN + kc + lq * 8];
#pragma unroll
      for (int i = 0; i < 4; ++i)
#pragma unroll
        for (int f = 0; f < 4; ++f)
          acc[i][f] = __builtin_amdgcn_mfma_f32_16x16x32_bf16(af[i], bfr[f],
                                                              acc[i][f], 0, 0, 0);
    }
    __syncthreads();
    if (layer < 3) {
#pragma unroll
      for (int i = 0; i < 4; ++i)
#pragma unroll
        for (int r = 0; r < 4; ++r) {
          const int row = i * 16 + lq * 4 + r;
#pragma unroll
          for (int f = 0; f < 4; ++f) {
            const int col = n0w + f * 16 + lr;
            X[row * XRS + col] = f2bf(fmaxf(acc[i][f][r] + bias[col], 0.f));
          }
        }
    } else {
#pragma unroll
      for (int i = 0; i < 4; ++i)
#pragma unroll
        for (int r = 0; r < 4; ++r) {
          const int row = i * 16 + lq * 4 + r;
          unsigned short* dst = refined_t + (size_t)rowoff[row];
#pragma unroll
          for (int f = 0; f < 4; ++f) {
            const int col = n0w + f * 16 + lr;
            dst[col] = f2bf(acc[i][f][r] + bias[col]);
          }
        }
    }
    __syncthreads();
  }
}

// ================= fuse GEMM + 2x bilinear upsample, fused ==================
// block = 16 channels x full 784 spatial of one n. K=256.
// B-frags direct from refined_t (L2/L3-resident); 28x28 maps staged in LDS;
// upsample epilogue writes out2 directly (no fused intermediate).
__global__ __launch_bounds__(256) void fuse_up_k(
    const unsigned short* __restrict__ refined_t, const unsigned short* __restrict__ wbf,
    const float* __restrict__ b_fuse, float* __restrict__ out2) {
  __shared__ __align__(16) unsigned short Abuf[16 * 268];  // 8.6 KB
  __shared__ float Fbuf[16 * 788];                         // 50.4 KB
  const int t = threadIdx.x;
  const int bx = blockIdx.x & 15, n = blockIdx.x >> 4;
  const int lane = t & 63, wave = t >> 6, lq = lane >> 4, lr = lane & 15;
  // stage A panel: w_fuse rows bx*16..+15 (16x256 bf16)
#pragma unroll
  for (int it = 0; it < 2; ++it) {
    const int u = it * 256 + t;
    const int row = u >> 5, col8 = (u & 31) * 8;
    *(short8*)&Abuf[row * 268 + col8] =
        *(const short8*)&wbf[OW_FUSE + ((bx * 16 + row) << 8) + col8];
  }
  const unsigned short* Bn = refined_t + (size_t)n * HW * 256;
  __syncthreads();
  f32x4 acc[13] = {};
  for (int kc = 0; kc < 256; kc += 32) {
    const short8 a = *(const short8*)&Abuf[lr * 268 + kc + lq * 8];
#pragma unroll
    for (int f = 0; f < 13; ++f) {
      const int s = (wave * 13 + f) * 16 + lr;
      const int sc = (s < HW) ? s : 0;
      const short8 b = *(const short8*)&Bn[(size_t)sc * 256 + kc + lq * 8];
      acc[f] = __builtin_amdgcn_mfma_f32_16x16x32_bf16(a, b, acc[f], 0, 0, 0);
    }
  }
  // epilogue: bias + relu -> Fbuf[cl][s]
#pragma unroll
  for (int f = 0; f < 13; ++f) {
    const int s = (wave * 13 + f) * 16 + lr;
    if (s < HW) {
#pragma unroll
      for (int r = 0; r < 4; ++r) {
        const int cl = lq * 4 + r;
        Fbuf[cl * 788 + s] = fmaxf(acc[f][r] + b_fuse[bx * 16 + cl], 0.f);
      }
    }
  }
  __syncthreads();
  // upsample 16 x 28x28 -> 16 x 56x56, write out2 directly
  float* dst = out2 + ((size_t)(n * CC + bx * 16)) * 3136;
  for (int cl = 0; cl < 16; ++cl) {
    const float* L = &Fbuf[cl * 788];
    for (int j = t; j < 3136; j += 256) {
      const int r = j / 56, q = j % 56;
      const float y = fminf(fmaxf(r * 0.5f - 0.25f, 0.f), 27.f);
      const float x = fminf(fmaxf(q * 0.5f - 0.25f, 0.f), 27.f);
      const int y0 = (int)y, x0 = (int)x;
      const float wy1 = y - (float)y0, wx1 = x - (float)x0;
      const int y1 = min(y0 + 1, 27), x1 = min(x0 + 1, 27);
      const float v00 = L[y0 * 28 + x0], v01 = L[y0 * 28 + x1];
      const float v10 = L[y1 * 28 + x0], v11 = L[y1 * 28 + x1];
      const float v = (1.f - wy1) * ((1.f - wx1) * v00 + wx1 * v01) +
                      wy1 * ((1.f - wx1) * v10 + wx1 * v11);
      dst[(size_t)cl * 3136 + j] = fmaxf(v, 0.f);
    }
  }
}

// ---------------- host launcher ----------------------------------------------
extern "C" void kernel_launch(void* const* d_in, const int* in_sizes, int n_in,
                              void* d_out, int out_size, void* d_ws, size_t ws_size,
                              hipStream_t stream) {
  (void)in_sizes; (void)n_in; (void)out_size; (void)ws_size;
  const float* inst   = (const float*)d_in[0];
  const float* semf   = (const float*)d_in[1];
  const float* rois   = (const float*)d_in[2];
  const int*   labels = (const int*)d_in[3];
  const float* w_sem  = (const float*)d_in[5];
  const float* b_sem  = (const float*)d_in[6];
  const float* w_inst = (const float*)d_in[7];
  const float* b_inst = (const float*)d_in[8];
  const float* w_det  = (const float*)d_in[9];
  const float* b_det  = (const float*)d_in[10];
  const float* fc_w0  = (const float*)d_in[11];
  const float* fc_b0  = (const float*)d_in[12];
  const float* fc_w1  = (const float*)d_in[13];
  const float* fc_b1  = (const float*)d_in[14];
  const float* fc_w2  = (const float*)d_in[15];
  const float* fc_b2  = (const float*)d_in[16];
  const float* w_log  = (const float*)d_in[17];
  const float* b_log  = (const float*)d_in[18];
  const float* w_fuse = (const float*)d_in[19];
  const float* b_fuse = (const float*)d_in[20];

  float* out0 = (float*)d_out;
  float* out1 = out0 + NN * HW;
  float* out2 = out0 + 2 * NN * HW;

  // workspace layout (float-offset units, all blocks 16B-aligned, no alias):
  float* ws = (float*)d_ws;
  int*   pidx               = (int*)ws;                             //     25,088 i
  unsigned short* semh      = (unsigned short*)(ws + 25088);        // 10,240,000 h
  unsigned short* semf_t    = (unsigned short*)(ws + 5145088);      // 10,240,000 h
  unsigned short* refined_t = (unsigned short*)(ws + 10265088);     // 25,690,112 h
  unsigned short* wbf       = (unsigned short*)(ws + 23110144);     //    598,016 h
  float* bcat               = ws + 23409152;                        //        160 f
  double* Pb0               = (double*)(ws + 23409312);             //    401,408 d
  double* Pb1               = (double*)(ws + 24212128);             //    401,408 d

  megaA_k<<<GA_TOT, 256, 0, stream>>>(semf, semf_t, inst, refined_t, labels,
                                      w_inst, w_det, Pb0, Pb1,
                                      w_sem, w_fuse, fc_w0, fc_w1, fc_w2, w_log,
                                      b_inst, b_det, wbf, bcat);
  megaB_k<<<GB_TOT, 256, 0, stream>>>(semf_t, wbf, b_sem, semh, Pb0, Pb1, labels,
                                      b_inst, b_det, out0, out1, pidx);
  fused_point_k<<<392, 256, 0, stream>>>(semh, refined_t, pidx, rois, wbf, bcat,
                                         fc_b0, fc_b1, fc_b2, b_log);
  fuse_up_k<<<NN * 16, 256, 0, stream>>>(refined_t, wbf, b_fuse, out2);
}